// Round 1
// baseline (254.284 us; speedup 1.0000x reference)
//
#include <hip/hip_runtime.h>
#include <math.h>

// Problem constants
#define HIDDEN 512
#define NHEADS 16
#define HDIM   32
#define BATCH  2
#define SEQ    1024
#define MROWS  (BATCH * SEQ)   // 2048

constexpr float LOG2_GAMMA = -0.15200309344504997f; // log2(0.9)
constexpr float INV_GAMMA  = 1.1111111111111112f;   // 1/0.9

// ---------------------------------------------------------------------------
// Tiled fp32 GEMM + bias: Y[M,N] = A[M,K] @ W[K,N] + bias[N]
// M=2048, N=512, K=512 fixed. 64x64 tile, 256 threads, 4x4 per thread.
// ---------------------------------------------------------------------------
__global__ __launch_bounds__(256) void gemm_bias(
    const float* __restrict__ A, const float* __restrict__ W,
    const float* __restrict__ bias, float* __restrict__ Y)
{
    constexpr int M = MROWS, N = HIDDEN, K = HIDDEN;
    __shared__ float As[64][17];   // +1 pad breaks the stride-16 bank pattern
    __shared__ float Bs[16][64];

    const int tid = threadIdx.x;
    const int tx = tid & 15;   // col group (4 cols each)
    const int ty = tid >> 4;   // row group (4 rows each)
    const int m0 = blockIdx.y * 64;
    const int n0 = blockIdx.x * 64;

    float acc[4][4] = {};

    for (int k0 = 0; k0 < K; k0 += 16) {
        // Stage A tile (64x16) and B tile (16x64); 256 float4 each.
        {
            const int rowa = tid >> 2;
            const int c4a  = (tid & 3) * 4;
            float4 av = *(const float4*)&A[(m0 + rowa) * K + k0 + c4a];
            As[rowa][c4a + 0] = av.x;
            As[rowa][c4a + 1] = av.y;
            As[rowa][c4a + 2] = av.z;
            As[rowa][c4a + 3] = av.w;
            const int rowb = tid >> 4;
            const int c4b  = (tid & 15) * 4;
            *(float4*)&Bs[rowb][c4b] = *(const float4*)&W[(k0 + rowb) * N + n0 + c4b];
        }
        __syncthreads();
        #pragma unroll
        for (int kk = 0; kk < 16; ++kk) {
            float a[4], b[4];
            #pragma unroll
            for (int i = 0; i < 4; ++i) a[i] = As[ty * 4 + i][kk];
            #pragma unroll
            for (int j = 0; j < 4; ++j) b[j] = Bs[kk][tx * 4 + j];
            #pragma unroll
            for (int i = 0; i < 4; ++i)
                #pragma unroll
                for (int j = 0; j < 4; ++j)
                    acc[i][j] += a[i] * b[j];
        }
        __syncthreads();
    }

    #pragma unroll
    for (int i = 0; i < 4; ++i) {
        const int m = m0 + ty * 4 + i;
        const int n = n0 + tx * 4;
        float4 o;
        o.x = acc[i][0] + bias[n + 0];
        o.y = acc[i][1] + bias[n + 1];
        o.z = acc[i][2] + bias[n + 2];
        o.w = acc[i][3] + bias[n + 3];
        *(float4*)&Y[m * N + n] = o;
    }
}

// ---------------------------------------------------------------------------
// Power attention: out[b,t,h,:] = sum_{s<=t} gamma^(t-s) * (q_t . k_s)^2 * v_s
// Uses spow2(q).spow2(k) == (q.k)^2 and gamma truncation (gamma^257 ~ 2e-12).
// Block: one 64-token chunk of one (b,h). 256 threads = 64 rows x 4 groups.
// ---------------------------------------------------------------------------
__global__ __launch_bounds__(256) void power_attn(
    const float* __restrict__ q, const float* __restrict__ k,
    const float* __restrict__ v, float* __restrict__ out)
{
    __shared__ float ks[64 * 32];
    __shared__ float vs[64 * 32];

    const int tid = threadIdx.x;
    const int r   = tid >> 2;   // local row 0..63
    const int g   = tid & 3;    // dim group (8 dims each)
    const int chunk = blockIdx.x;
    const int bh  = blockIdx.y;
    const int b   = bh >> 4;
    const int h   = bh & 15;
    const int t   = chunk * 64 + r;
    const int m   = b * SEQ + t;
    const int col = h * HDIM + g * 8;

    // q fragment lives in registers for the whole block
    float qreg[8];
    {
        float4 q0 = *(const float4*)&q[m * HIDDEN + col];
        float4 q1 = *(const float4*)&q[m * HIDDEN + col + 4];
        qreg[0] = q0.x; qreg[1] = q0.y; qreg[2] = q0.z; qreg[3] = q0.w;
        qreg[4] = q1.x; qreg[5] = q1.y; qreg[6] = q1.z; qreg[7] = q1.w;
    }
    float acc[8] = {0.f, 0.f, 0.f, 0.f, 0.f, 0.f, 0.f, 0.f};

    const int jstart = chunk > 4 ? chunk - 4 : 0;   // window: max lag 319
    for (int j = jstart; j <= chunk; ++j) {
        __syncthreads();
        // Stage K and V tiles (64x32 each): 512 float4 per array, 2/thread.
        #pragma unroll
        for (int u = 0; u < 2; ++u) {
            const int ff  = tid + u * 256;
            const int row = ff >> 3;
            const int c4  = (ff & 7) * 4;
            const int sm  = b * SEQ + j * 64 + row;
            *(float4*)&ks[row * 32 + c4] = *(const float4*)&k[sm * HIDDEN + h * HDIM + c4];
            *(float4*)&vs[row * 32 + c4] = *(const float4*)&v[sm * HIDDEN + h * HDIM + c4];
        }
        __syncthreads();

        const int lim = (j == chunk) ? r : 63;
        float decay = exp2f((float)(t - j * 64) * LOG2_GAMMA);  // gamma^(lag at ss=0)
        for (int ss = 0; ss <= lim; ++ss) {
            // partial dot over this thread's 8 dims; reduce across the 4 groups
            float partial = 0.f;
            const float* kr = &ks[ss * 32 + g * 8];
            #pragma unroll
            for (int i = 0; i < 8; ++i) partial += qreg[i] * kr[i];
            partial += __shfl_xor(partial, 1);
            partial += __shfl_xor(partial, 2);
            const float p = partial * partial * decay;
            const float* vr = &vs[ss * 32 + g * 8];
            #pragma unroll
            for (int i = 0; i < 8; ++i) acc[i] += p * vr[i];
            decay *= INV_GAMMA;
        }
    }

    float4 o0 = {acc[0], acc[1], acc[2], acc[3]};
    float4 o1 = {acc[4], acc[5], acc[6], acc[7]};
    *(float4*)&out[m * HIDDEN + col]     = o0;
    *(float4*)&out[m * HIDDEN + col + 4] = o1;
}

// ---------------------------------------------------------------------------
extern "C" void kernel_launch(void* const* d_in, const int* in_sizes, int n_in,
                              void* d_out, int out_size, void* d_ws, size_t ws_size,
                              hipStream_t stream)
{
    const float* x  = (const float*)d_in[0];
    const float* qw = (const float*)d_in[1];
    const float* qb = (const float*)d_in[2];
    const float* kw = (const float*)d_in[3];
    const float* kb = (const float*)d_in[4];
    const float* vw = (const float*)d_in[5];
    const float* vb = (const float*)d_in[6];
    const float* ow = (const float*)d_in[7];
    const float* ob = (const float*)d_in[8];
    float* out = (float*)d_out;

    float* ws = (float*)d_ws;
    float* q  = ws;
    float* kk = ws + (size_t)MROWS * HIDDEN;
    float* vv = ws + (size_t)2 * MROWS * HIDDEN;
    float* at = ws + (size_t)3 * MROWS * HIDDEN;   // 16 MB total fp32 scratch

    dim3 gg(HIDDEN / 64, MROWS / 64);   // (8, 32)
    gemm_bias<<<gg, 256, 0, stream>>>(x, qw, qb, q);
    gemm_bias<<<gg, 256, 0, stream>>>(x, kw, kb, kk);
    gemm_bias<<<gg, 256, 0, stream>>>(x, vw, vb, vv);

    power_attn<<<dim3(SEQ / 64, BATCH * NHEADS), 256, 0, stream>>>(q, kk, vv, at);

    gemm_bias<<<gg, 256, 0, stream>>>(at, ow, ob, out);
}

// Round 2
// 164.631 us; speedup vs baseline: 1.5446x; 1.5446x over previous
//
#include <hip/hip_runtime.h>
#include <hip/hip_bf16.h>
#include <math.h>

// Problem constants
#define HIDDEN 512
#define NHEADS 16
#define HDIM   32
#define BATCH  2
#define SEQ    1024
#define MROWS  (BATCH * SEQ)   // 2048

constexpr float LOG2_GAMMA = -0.15200309344504997f; // log2(0.9)
constexpr float INV_GAMMA  = 1.1111111111111112f;   // 1/0.9

typedef __hip_bfloat16 bf16;
typedef __attribute__((ext_vector_type(8))) short short8;
typedef __attribute__((ext_vector_type(4))) float f32x4;

// ---------------------------------------------------------------------------
// async global->LDS 16B copy. LDS dest must be wave-uniform base; lane i's
// 16 bytes land at base + i*16 (no per-lane scatter!).
// ---------------------------------------------------------------------------
__device__ __forceinline__ void async16(const bf16* g, bf16* l) {
    __builtin_amdgcn_global_load_lds(
        (__attribute__((address_space(1))) void*)g,
        (__attribute__((address_space(3))) void*)l, 16, 0, 0);
}

// ---------------------------------------------------------------------------
// x (fp32 [M][512]) -> xcat (bf16 [M][1024]) = [hi | lo residual] along K.
// ---------------------------------------------------------------------------
__global__ __launch_bounds__(256) void cast_split(
    const float* __restrict__ x, bf16* __restrict__ xc, int rows)
{
    const int t = blockIdx.x * 256 + threadIdx.x;   // rows*128 threads
    if (t >= rows * 128) return;
    const int m = t >> 7;
    const int c = (t & 127) * 4;
    float4 v = *(const float4*)&x[(size_t)m * 512 + c];
    float vals[4] = {v.x, v.y, v.z, v.w};
    bf16 hi[4], lo[4];
    #pragma unroll
    for (int i = 0; i < 4; ++i) {
        hi[i] = __float2bfloat16(vals[i]);
        lo[i] = __float2bfloat16(vals[i] - __bfloat162float(hi[i]));
    }
    *(ulong1*)&xc[(size_t)m * 1024 + c]       = *(ulong1*)hi;
    *(ulong1*)&xc[(size_t)m * 1024 + 512 + c] = *(ulong1*)lo;
}

// ---------------------------------------------------------------------------
// Transpose+cast+duplicate: w (fp32 [512][512] K-major) -> o (bf16 [512][1024])
// where o[n][k] = o[n][512+k] = bf16(w[k][n]).  blockIdx.z selects one of 4.
// ---------------------------------------------------------------------------
__global__ __launch_bounds__(256) void transpose_cast_dup(
    const float* __restrict__ w0, const float* __restrict__ w1,
    const float* __restrict__ w2, const float* __restrict__ w3,
    bf16* __restrict__ o0, bf16* __restrict__ o1,
    bf16* __restrict__ o2, bf16* __restrict__ o3)
{
    const float* w; bf16* o;
    switch (blockIdx.z) {
        case 0: w = w0; o = o0; break;
        case 1: w = w1; o = o1; break;
        case 2: w = w2; o = o2; break;
        default: w = w3; o = o3; break;
    }
    __shared__ float t[64][65];
    const int tid = threadIdx.x;
    const int k0 = blockIdx.x * 64, n0 = blockIdx.y * 64;
    #pragma unroll
    for (int u = 0; u < 4; ++u) {
        const int idx = tid + u * 256;
        const int r = idx >> 4, c = (idx & 15) * 4;
        float4 v = *(const float4*)&w[(size_t)(k0 + r) * 512 + n0 + c];
        t[r][c + 0] = v.x; t[r][c + 1] = v.y; t[r][c + 2] = v.z; t[r][c + 3] = v.w;
    }
    __syncthreads();
    #pragma unroll
    for (int u = 0; u < 2; ++u) {
        const int idx = tid + u * 256;
        const int r = idx >> 3, c = (idx & 7) * 8;
        alignas(16) bf16 tmp[8];
        #pragma unroll
        for (int i = 0; i < 8; ++i) tmp[i] = __float2bfloat16(t[c + i][r]);
        *(short8*)&o[(size_t)(n0 + r) * 1024 + k0 + c]       = *(short8*)tmp;
        *(short8*)&o[(size_t)(n0 + r) * 1024 + 512 + k0 + c] = *(short8*)tmp;
    }
}

__global__ __launch_bounds__(256) void fuse_bias(
    const float* __restrict__ qb, const float* __restrict__ kb,
    const float* __restrict__ vb, float* __restrict__ out)
{
    const int i = blockIdx.x * 256 + threadIdx.x;
    if (i < 512) out[i] = qb[i];
    else if (i < 1024) out[i] = kb[i - 512];
    else if (i < 1536) out[i] = vb[i - 1024];
}

// ---------------------------------------------------------------------------
// bf16 MFMA GEMM: C[M][ldc] = A[M][KDIM] @ Bt[N][KDIM]^T + bias[N]  (fp32 out)
// BM x BN block tile, BK=32, 4 waves in 2x2, 16x16x32 MFMA.
// ---------------------------------------------------------------------------
template<int BM, int BN, int KDIM>
__global__ __launch_bounds__(256) void gemm_mfma(
    const bf16* __restrict__ A, const bf16* __restrict__ Bt,
    const float* __restrict__ bias, float* __restrict__ C, int ldc)
{
    constexpr int BK = 32;
    constexpr int TM = BM / 32, TN = BN / 32;
    __shared__ alignas(16) bf16 As[BM * BK];
    __shared__ alignas(16) bf16 Bs[BN * BK];

    const int tid = threadIdx.x;
    const int wave = tid >> 6, lane = tid & 63;
    const int m0 = blockIdx.y * BM, n0 = blockIdx.x * BN;
    const int wm = (wave >> 1) * (BM / 2), wn = (wave & 1) * (BN / 2);
    const int fr = lane & 15;             // fragment row (m or n)
    const int fk = (lane >> 4) * 8;       // fragment k offset
    const int lrow = lane >> 2;           // staging: row within 16-row group
    const int lk = (lane & 3) * 8;        // staging: k offset (8 bf16 = 16B)

    f32x4 acc[TM][TN] = {};

    for (int k0 = 0; k0 < KDIM; k0 += BK) {
        // ---- stage A (BM x 32) and B (BN x 32), row-major [r][k], k-contig
        #pragma unroll
        for (int u = 0; u < BM / 64; ++u) {
            const int rb = (wave * (BM / 64) + u) * 16;
            async16(&A[(size_t)(m0 + rb + lrow) * KDIM + k0 + lk], &As[rb * BK]);
        }
        #pragma unroll
        for (int u = 0; u < BN / 64; ++u) {
            const int rb = (wave * (BN / 64) + u) * 16;
            async16(&Bt[(size_t)(n0 + rb + lrow) * KDIM + k0 + lk], &Bs[rb * BK]);
        }
        __syncthreads();   // compiler inserts vmcnt(0) drain before barrier

        short8 af[TM], bfr[TN];
        #pragma unroll
        for (int i = 0; i < TM; ++i)
            af[i] = *(const short8*)&As[(wm + i * 16 + fr) * BK + fk];
        #pragma unroll
        for (int j = 0; j < TN; ++j)
            bfr[j] = *(const short8*)&Bs[(wn + j * 16 + fr) * BK + fk];
        #pragma unroll
        for (int i = 0; i < TM; ++i)
            #pragma unroll
            for (int j = 0; j < TN; ++j)
                acc[i][j] = __builtin_amdgcn_mfma_f32_16x16x32_bf16(
                    af[i], bfr[j], acc[i][j], 0, 0, 0);
        __syncthreads();
    }

    // Epilogue. C/D layout: col(n)=lane&15, row(m)=(lane>>4)*4+reg.
    #pragma unroll
    for (int j = 0; j < TN; ++j) {
        const int n = n0 + wn + j * 16 + fr;
        const float bv = bias[n];
        #pragma unroll
        for (int i = 0; i < TM; ++i) {
            const int mr = m0 + wm + i * 16 + (lane >> 4) * 4;
            #pragma unroll
            for (int r = 0; r < 4; ++r)
                C[(size_t)(mr + r) * ldc + n] = acc[i][j][r] + bv;
        }
    }
}

// ---------------------------------------------------------------------------
// Power attention on fused qkv [M][1536] fp32:
// out[b,t,h,:] = sum_{s<=t} gamma^(t-s) * (q_t . k_s)^2 * v_s
// Writes bf16 hi|lo split into atc [M][1024] for the output GEMM.
// ---------------------------------------------------------------------------
__global__ __launch_bounds__(256) void power_attn(
    const float* __restrict__ qkv, bf16* __restrict__ atc)
{
    __shared__ float ks[64 * 32];
    __shared__ float vs[64 * 32];

    const int tid = threadIdx.x;
    const int r   = tid >> 2;   // local row 0..63
    const int g   = tid & 3;    // dim group (8 dims each)
    const int chunk = blockIdx.x;
    const int bh  = blockIdx.y;
    const int b   = bh >> 4;
    const int h   = bh & 15;
    const int t   = chunk * 64 + r;
    const int m   = b * SEQ + t;
    const int qc  = h * HDIM + g * 8;          // q col within [0,512)

    float qreg[8];
    {
        float4 q0 = *(const float4*)&qkv[(size_t)m * 1536 + qc];
        float4 q1 = *(const float4*)&qkv[(size_t)m * 1536 + qc + 4];
        qreg[0] = q0.x; qreg[1] = q0.y; qreg[2] = q0.z; qreg[3] = q0.w;
        qreg[4] = q1.x; qreg[5] = q1.y; qreg[6] = q1.z; qreg[7] = q1.w;
    }
    float acc[8] = {};

    const int jstart = chunk > 4 ? chunk - 4 : 0;   // gamma^320 ~ 2e-15
    for (int j = jstart; j <= chunk; ++j) {
        __syncthreads();
        #pragma unroll
        for (int u = 0; u < 2; ++u) {
            const int ff  = tid + u * 256;
            const int row = ff >> 3;
            const int c4  = (ff & 7) * 4;
            const size_t sm = (size_t)(b * SEQ + j * 64 + row) * 1536;
            *(float4*)&ks[row * 32 + c4] = *(const float4*)&qkv[sm + 512 + h * HDIM + c4];
            *(float4*)&vs[row * 32 + c4] = *(const float4*)&qkv[sm + 1024 + h * HDIM + c4];
        }
        __syncthreads();

        const int lim = (j == chunk) ? r : 63;
        float decay = exp2f((float)(t - j * 64) * LOG2_GAMMA);
        for (int ss = 0; ss <= lim; ++ss) {
            float partial = 0.f;
            const float* kr = &ks[ss * 32 + g * 8];
            #pragma unroll
            for (int i = 0; i < 8; ++i) partial += qreg[i] * kr[i];
            partial += __shfl_xor(partial, 1);
            partial += __shfl_xor(partial, 2);
            const float p = partial * partial * decay;
            const float* vr = &vs[ss * 32 + g * 8];
            #pragma unroll
            for (int i = 0; i < 8; ++i) acc[i] += p * vr[i];
            decay *= INV_GAMMA;
        }
    }

    alignas(16) bf16 hi[8], lo[8];
    #pragma unroll
    for (int i = 0; i < 8; ++i) {
        hi[i] = __float2bfloat16(acc[i]);
        lo[i] = __float2bfloat16(acc[i] - __bfloat162float(hi[i]));
    }
    *(short8*)&atc[(size_t)m * 1024 + qc]       = *(short8*)hi;
    *(short8*)&atc[(size_t)m * 1024 + 512 + qc] = *(short8*)lo;
}

// ---------------------------------------------------------------------------
extern "C" void kernel_launch(void* const* d_in, const int* in_sizes, int n_in,
                              void* d_out, int out_size, void* d_ws, size_t ws_size,
                              hipStream_t stream)
{
    const float* x  = (const float*)d_in[0];
    const float* qw = (const float*)d_in[1];
    const float* qb = (const float*)d_in[2];
    const float* kw = (const float*)d_in[3];
    const float* kb = (const float*)d_in[4];
    const float* vw = (const float*)d_in[5];
    const float* vb = (const float*)d_in[6];
    const float* ow = (const float*)d_in[7];
    const float* ob = (const float*)d_in[8];
    float* out = (float*)d_out;

    // workspace carve-up (bytes)
    char* w = (char*)d_ws;
    bf16*  xcat  = (bf16*)(w);                              // 4 MB  [2048][1024]
    bf16*  wtqkv = (bf16*)(w + (4ull << 20));               // 3 MB  [1536][1024]
    bf16*  wto   = (bf16*)(w + (7ull << 20));               // 1 MB  [512][1024]
    float* bqkv  = (float*)(w + (8ull << 20));              // 6 KB  [1536]
    float* qkv   = (float*)(w + (8ull << 20) + (1ull << 16)); // 12 MB [2048][1536]
    bf16*  atc   = (bf16*)(w + (20ull << 20) + (1ull << 16)); // 4 MB [2048][1024]

    cast_split<<<MROWS * 128 / 256, 256, 0, stream>>>(x, xcat, MROWS);
    transpose_cast_dup<<<dim3(8, 8, 4), 256, 0, stream>>>(
        qw, kw, vw, ow,
        wtqkv, wtqkv + (size_t)512 * 1024, wtqkv + (size_t)1024 * 1024, wto);
    fuse_bias<<<6, 256, 0, stream>>>(qb, kb, vb, bqkv);

    // QKV fused GEMM: [2048][1024] x [1536][1024]^T -> [2048][1536]
    gemm_mfma<128, 64, 1024><<<dim3(1536 / 64, MROWS / 128), 256, 0, stream>>>(
        xcat, wtqkv, bqkv, qkv, 1536);

    power_attn<<<dim3(SEQ / 64, BATCH * NHEADS), 256, 0, stream>>>(qkv, atc);

    // Output GEMM: [2048][1024] x [512][1024]^T -> [2048][512]
    gemm_mfma<128, 64, 1024><<<dim3(512 / 64, MROWS / 128), 256, 0, stream>>>(
        atc, wto, ob, out, 512);
}

// Round 3
// 99.169 us; speedup vs baseline: 2.5642x; 1.6601x over previous
//
#include <hip/hip_runtime.h>
#include <hip/hip_bf16.h>
#include <math.h>

// Problem constants
#define HIDDEN 512
#define NHEADS 16
#define HDIM   32
#define BATCH  2
#define SEQ    1024
#define MROWS  (BATCH * SEQ)   // 2048

constexpr float LOG2_GAMMA = -0.15200309344504997f; // log2(0.9)

typedef __hip_bfloat16 bf16;
typedef __attribute__((ext_vector_type(8))) short short8;
typedef __attribute__((ext_vector_type(4))) float f32x4;

__device__ __forceinline__ void async16(const void* g, void* l) {
    __builtin_amdgcn_global_load_lds(
        (const __attribute__((address_space(1))) void*)g,
        (__attribute__((address_space(3))) void*)l, 16, 0, 0);
}

__device__ __forceinline__ unsigned short f2bf_bits(float f) {
    bf16 b = __float2bfloat16(f);
    return *(unsigned short*)&b;
}

// ---------------------------------------------------------------------------
// Fused prep: blocks 0-255 transpose+cast the 4 weights (fp32 [512 k][512 n]
// -> bf16 [n][512 k]); blocks 256-511 cast x fp32 -> bf16.
// ---------------------------------------------------------------------------
__global__ __launch_bounds__(256) void prep(
    const float* __restrict__ x,
    const float* __restrict__ qw, const float* __restrict__ kw,
    const float* __restrict__ vw, const float* __restrict__ ow,
    bf16* __restrict__ xb, bf16* __restrict__ wqkvt, bf16* __restrict__ wot)
{
    const int blk = blockIdx.x, tid = threadIdx.x;
    if (blk < 256) {
        const int widx = blk >> 6;
        const int tile = blk & 63;
        const int tk = (tile & 7) * 64, tn = (tile >> 3) * 64;
        const float* w = widx == 0 ? qw : widx == 1 ? kw : widx == 2 ? vw : ow;
        __shared__ float t[64][65];
        #pragma unroll
        for (int u = 0; u < 4; ++u) {
            const int r = u * 16 + (tid >> 4);
            const int c = (tid & 15) * 4;
            float4 v = *(const float4*)&w[(size_t)(tk + r) * 512 + tn + c];
            t[r][c + 0] = v.x; t[r][c + 1] = v.y; t[r][c + 2] = v.z; t[r][c + 3] = v.w;
        }
        __syncthreads();
        #pragma unroll
        for (int u = 0; u < 2; ++u) {
            const int rr = u * 32 + (tid >> 3);
            const int cc = (tid & 7) * 8;
            alignas(16) unsigned short tmp[8];
            #pragma unroll
            for (int i = 0; i < 8; ++i) tmp[i] = f2bf_bits(t[cc + i][rr]);
            bf16* dst = (widx < 3)
                ? &wqkvt[((size_t)widx * 512 + tn + rr) * 512 + tk + cc]
                : &wot[(size_t)(tn + rr) * 512 + tk + cc];
            *(short8*)dst = *(short8*)tmp;
        }
    } else {
        // cast x: 2048*512 fp32 -> bf16; 256 blocks x 1024 float4
        #pragma unroll
        for (int u = 0; u < 4; ++u) {
            const int idx = (blk - 256) * 1024 + u * 256 + tid;
            float4 v = ((const float4*)x)[idx];
            unsigned pk0 = (unsigned)f2bf_bits(v.x) | ((unsigned)f2bf_bits(v.y) << 16);
            unsigned pk1 = (unsigned)f2bf_bits(v.z) | ((unsigned)f2bf_bits(v.w) << 16);
            uint2 pk = {pk0, pk1};
            *(uint2*)&xb[(size_t)idx * 4] = pk;
        }
    }
}

// ---------------------------------------------------------------------------
// bf16 MFMA GEMM, K=512, BK=32, 4 waves 2x2.
// EPI=1 (QKV): out bf16 with per-row gamma scale folded in + segmented bias.
//   seg 0 (q): *(gamma^((m&63)/2)); seg 1 (k): *(gamma^(-(m&63)/2)); seg 2 (v): 1.
// EPI=0 (out-proj): fp32 out + bias.
// ---------------------------------------------------------------------------
template<int BM, int BN, int EPI>
__global__ __launch_bounds__(256) void gemm_mfma(
    const bf16* __restrict__ A, const bf16* __restrict__ Bt,
    const float* __restrict__ b0, const float* __restrict__ b1,
    const float* __restrict__ b2,
    float* __restrict__ Cf, bf16* __restrict__ Cb, int ldc)
{
    constexpr int K = 512, BK = 32;
    constexpr int TM = BM / 32, TN = BN / 32;
    __shared__ alignas(16) short As[BM * BK];
    __shared__ alignas(16) short Bs[BN * BK];

    const int tid = threadIdx.x;
    const int wave = tid >> 6, lane = tid & 63;
    const int m0 = blockIdx.y * BM, n0 = blockIdx.x * BN;
    const int wm = (wave >> 1) * (BM / 2), wn = (wave & 1) * (BN / 2);
    const int fr = lane & 15, quad = lane >> 4;
    const int fk = quad * 8;
    const int lrow = lane >> 2, lk = (lane & 3) * 8;

    f32x4 acc[TM][TN] = {};

    for (int k0 = 0; k0 < K; k0 += BK) {
        #pragma unroll
        for (int u = 0; u < BM / 64; ++u) {
            const int rb = (wave * (BM / 64) + u) * 16;
            async16(&A[(size_t)(m0 + rb + lrow) * K + k0 + lk], &As[rb * BK]);
        }
        #pragma unroll
        for (int u = 0; u < BN / 64; ++u) {
            const int rb = (wave * (BN / 64) + u) * 16;
            async16(&Bt[(size_t)(n0 + rb + lrow) * K + k0 + lk], &Bs[rb * BK]);
        }
        __syncthreads();

        short8 af[TM], bfr[TN];
        #pragma unroll
        for (int i = 0; i < TM; ++i)
            af[i] = *(const short8*)&As[(wm + i * 16 + fr) * BK + fk];
        #pragma unroll
        for (int j = 0; j < TN; ++j)
            bfr[j] = *(const short8*)&Bs[(wn + j * 16 + fr) * BK + fk];
        #pragma unroll
        for (int i = 0; i < TM; ++i)
            #pragma unroll
            for (int j = 0; j < TN; ++j)
                acc[i][j] = __builtin_amdgcn_mfma_f32_16x16x32_bf16(
                    af[i], bfr[j], acc[i][j], 0, 0, 0);
        __syncthreads();
    }

    // Epilogue. C/D layout: col(n)=lane&15, row(m)=quad*4+reg.
    if (EPI == 1) {
        const int seg = (blockIdx.x * BN) >> 9;   // block-uniform q/k/v segment
        const float* bp = seg == 0 ? b0 : seg == 1 ? b1 : b2;
        const float sgn = seg == 0 ? 0.5f : seg == 1 ? -0.5f : 0.0f;
        #pragma unroll
        for (int i = 0; i < TM; ++i) {
            const int mrow = m0 + wm + i * 16 + quad * 4;
            float sc[4];
            #pragma unroll
            for (int r = 0; r < 4; ++r)
                sc[r] = exp2f((float)((mrow + r) & 63) * (sgn * LOG2_GAMMA));
            #pragma unroll
            for (int j = 0; j < TN; ++j) {
                const int n = n0 + wn + j * 16 + fr;
                const float bv = bp[n & 511];
                #pragma unroll
                for (int r = 0; r < 4; ++r) {
                    unsigned short h = f2bf_bits((acc[i][j][r] + bv) * sc[r]);
                    *(unsigned short*)&Cb[(size_t)(mrow + r) * ldc + n] = h;
                }
            }
        }
    } else {
        #pragma unroll
        for (int i = 0; i < TM; ++i) {
            const int mrow = m0 + wm + i * 16 + quad * 4;
            #pragma unroll
            for (int j = 0; j < TN; ++j) {
                const int n = n0 + wn + j * 16 + fr;
                const float bv = b0[n];
                #pragma unroll
                for (int r = 0; r < 4; ++r)
                    Cf[(size_t)(mrow + r) * ldc + n] = acc[i][j][r] + bv;
            }
        }
    }
}

// ---------------------------------------------------------------------------
// MFMA power attention. Block = (chunk of 64 tokens) x (b,h). 4 waves; wave w
// owns Q/O rows w*16..w*16+15. Decay row-scales are pre-folded into q,k by
// the QKV GEMM; here: S = Q@K^T (K=32), P = S^2 * gamma^(64*(chunk-j)) with
// causal mask on the diagonal chunk, LDS round-trip to A-layout, O += P@V.
// ---------------------------------------------------------------------------
__global__ __launch_bounds__(256) void power_attn_mfma(
    const bf16* __restrict__ qkv, bf16* __restrict__ atc)
{
    __shared__ alignas(16) short Qs[64 * 32];
    __shared__ alignas(16) short Ks[64 * 32];
    __shared__ alignas(16) short Vt[32 * 80];   // V transposed [d][s], stride 80
    __shared__ alignas(16) short Ps[64 * 72];   // P [t][s], stride 72 (16B-aligned rows)

    const int tid = threadIdx.x, wave = tid >> 6, lane = tid & 63;
    const int chunk = blockIdx.x, bh = blockIdx.y;
    const int b = bh >> 4, h = bh & 15;
    const int mb = b * SEQ + chunk * 64;
    const int fr = lane & 15, quad = lane >> 4;

    // stage Q once (wave w stages its own 16 rows)
    async16(&qkv[(size_t)(mb + wave * 16 + (lane >> 2)) * 1536 + h * 32 + (lane & 3) * 8],
            &Qs[wave * 512]);

    f32x4 o0 = {}, o1 = {};
    const int jstart = chunk >= 2 ? chunk - 2 : 0;   // gamma^129 ~ 1e-6: negligible

    for (int j = jstart; j <= chunk; ++j) {
        __syncthreads();   // protect Ks/Vt from previous iteration's readers
        const int sb = b * SEQ + j * 64;
        async16(&qkv[(size_t)(sb + wave * 16 + (lane >> 2)) * 1536 + 512 + h * 32 + (lane & 3) * 8],
                &Ks[wave * 512]);
        if (tid < 128) {   // transpose-stage V: pairs of s packed as b32 writes
            const int p = tid >> 2, s = p * 2, dbase = (tid & 3) * 8;
            const short* g = (const short*)&qkv[(size_t)(sb + s) * 1536 + 1024 + h * 32 + dbase];
            short8 v0 = *(const short8*)g;
            short8 v1 = *(const short8*)(g + 1536);
            #pragma unroll
            for (int i = 0; i < 8; ++i) {
                unsigned pk = (unsigned)(unsigned short)v0[i]
                            | ((unsigned)(unsigned short)v1[i] << 16);
                *(unsigned*)&Vt[(dbase + i) * 80 + s] = pk;
            }
        }
        __syncthreads();

        // S = Q @ K^T : per wave 16x64, one K=32 step
        short8 aq = *(const short8*)&Qs[(wave * 16 + fr) * 32 + quad * 8];
        f32x4 sAcc[4] = {};
        #pragma unroll
        for (int nt = 0; nt < 4; ++nt) {
            short8 bk = *(const short8*)&Ks[(nt * 16 + fr) * 32 + quad * 8];
            sAcc[nt] = __builtin_amdgcn_mfma_f32_16x16x32_bf16(aq, bk, sAcc[nt], 0, 0, 0);
        }

        const int dj = chunk - j;
        const float sj = exp2f(64.0f * (float)dj * LOG2_GAMMA);
        const int tbase = wave * 16 + quad * 4;
        #pragma unroll
        for (int nt = 0; nt < 4; ++nt) {
            const int s_l = nt * 16 + fr;
            #pragma unroll
            for (int r = 0; r < 4; ++r) {
                const int t_l = tbase + r;
                float pv = sAcc[nt][r];
                pv = pv * pv * sj;
                if (dj == 0 && s_l > t_l) pv = 0.0f;
                Ps[t_l * 72 + s_l] = (short)f2bf_bits(pv);
            }
        }
        // same-wave write->read: compiler inserts lgkmcnt wait; wave reads only
        // its own 16-row Ps region.
        short8 a0 = *(const short8*)&Ps[(wave * 16 + fr) * 72 + quad * 8];
        short8 a1 = *(const short8*)&Ps[(wave * 16 + fr) * 72 + 32 + quad * 8];
        short8 b00 = *(const short8*)&Vt[fr * 80 + quad * 8];
        short8 b01 = *(const short8*)&Vt[fr * 80 + 32 + quad * 8];
        short8 b10 = *(const short8*)&Vt[(16 + fr) * 80 + quad * 8];
        short8 b11 = *(const short8*)&Vt[(16 + fr) * 80 + 32 + quad * 8];
        o0 = __builtin_amdgcn_mfma_f32_16x16x32_bf16(a0, b00, o0, 0, 0, 0);
        o0 = __builtin_amdgcn_mfma_f32_16x16x32_bf16(a1, b01, o0, 0, 0, 0);
        o1 = __builtin_amdgcn_mfma_f32_16x16x32_bf16(a0, b10, o1, 0, 0, 0);
        o1 = __builtin_amdgcn_mfma_f32_16x16x32_bf16(a1, b11, o1, 0, 0, 0);
    }

    #pragma unroll
    for (int r = 0; r < 4; ++r) {
        const size_t row = mb + wave * 16 + quad * 4 + r;
        const int col = h * 32 + fr;
        *(unsigned short*)&atc[row * 512 + col]      = f2bf_bits(o0[r]);
        *(unsigned short*)&atc[row * 512 + col + 16] = f2bf_bits(o1[r]);
    }
}

// ---------------------------------------------------------------------------
extern "C" void kernel_launch(void* const* d_in, const int* in_sizes, int n_in,
                              void* d_out, int out_size, void* d_ws, size_t ws_size,
                              hipStream_t stream)
{
    const float* x  = (const float*)d_in[0];
    const float* qw = (const float*)d_in[1];
    const float* qb = (const float*)d_in[2];
    const float* kw = (const float*)d_in[3];
    const float* kb = (const float*)d_in[4];
    const float* vw = (const float*)d_in[5];
    const float* vb = (const float*)d_in[6];
    const float* ow = (const float*)d_in[7];
    const float* ob = (const float*)d_in[8];
    float* out = (float*)d_out;

    char* w = (char*)d_ws;
    bf16* xb    = (bf16*)(w);                    // 2 MB   [2048][512]
    bf16* wqkvt = (bf16*)(w + (2ull  << 20));    // 1.5 MB [1536][512]
    bf16* wot   = (bf16*)(w + (2ull  << 20) + (1536ull << 10)); // 0.5 MB [512][512]
    bf16* qkvb  = (bf16*)(w + (4ull  << 20));    // 6 MB   [2048][1536]
    bf16* atc   = (bf16*)(w + (10ull << 20));    // 2 MB   [2048][512]

    prep<<<512, 256, 0, stream>>>(x, qw, kw, vw, ow, xb, wqkvt, wot);

    // QKV GEMM: [2048][512] x [1536][512]^T -> bf16 [2048][1536] (scaled)
    gemm_mfma<128, 64, 1><<<dim3(1536 / 64, MROWS / 128), 256, 0, stream>>>(
        xb, wqkvt, qb, kb, vb, nullptr, qkvb, 1536);

    power_attn_mfma<<<dim3(SEQ / 64, BATCH * NHEADS), 256, 0, stream>>>(qkvb, atc);

    // Output GEMM: [2048][512] x [512][512]^T -> fp32 out
    gemm_mfma<64, 64, 0><<<dim3(512 / 64, MROWS / 64), 256, 0, stream>>>(
        atc, wot, ob, nullptr, nullptr, out, nullptr, 512);
}